// Round 12
// baseline (2962.337 us; speedup 1.0000x reference)
//
#include <hip/hip_runtime.h>
#include <hip/hip_fp8.h>

// ---------------------------------------------------------------------------
// FusedSparseLMHead: weighted-mean CE over h @ W^T without materializing logits.
//   h: [4096, 2048] f32, W: [65536, 2048] f32, labels: [4096] int, w: [4096] f32
// Round 12: fp8-e4m3 GEMM via mfma_scale_f32_16x16x128_f8f6f4 with IDENTITY
//   scales (all E8M0 bytes 0x7F = 1.0 -> scale layout irrelevant).
//   Inputs pre-scaled: h*16, W*64 (avoids e4m3 denormals); epilogue logits
//   * 1/1024 in f32. Label logit exact fp32 (unchanged).
//   Structure = r11's verified 8-phase: BK=128 fp8 (128 B/row), 2-buf A + 2-buf
//   B (128 KB), LDS[r][c16] = G[r][c16^(r&7)] both-sides swizzle (r8-measured
//   0-conflict shape), A staged 1 ahead (ph0/ph1), B staged 2 ahead (ph2/ph3),
//   boundary vmcnt(4) counted (r11 queue proof holds verbatim: at boundary(t)
//   queue = [B(t+1)4, A(t+1)4, B(t+2)4]; vmcnt(4) forces A(t+1),B(t+1)).
// ---------------------------------------------------------------------------

typedef __attribute__((ext_vector_type(4)))  float f32x4;
typedef __attribute__((ext_vector_type(8)))  float f32x8;
typedef __attribute__((ext_vector_type(8)))  int   i32x8;
typedef __attribute__((ext_vector_type(4)))  int   i32x4;

#define N_TOK 4096
#define DIM   2048          // == row bytes in fp8
#define VOCAB 65536
#define BM    256
#define BN    256
#define BK    128           // fp8 elements per K-tile
#define NT    (DIM / BK)    // 16 K-tiles
#define NCH   (VOCAB / BN)  // 256 vocab chunks
#define NTB   (N_TOK / BM)  // 16 token blocks
#define IDSC  0x7F7F7F7F    // identity E8M0 scales (2^0)

__device__ __forceinline__ void gload_lds16(const void* g, void* l) {
    __builtin_amdgcn_global_load_lds(
        (const __attribute__((address_space(1))) void*)g,
        (__attribute__((address_space(3))) void*)l, 16, 0, 0);
}

__device__ __forceinline__ void bar() {
    asm volatile("" ::: "memory");
    __builtin_amdgcn_s_barrier();
    asm volatile("" ::: "memory");
}

// ------------------------------------------------------------ convert fp8 ---
__global__ __launch_bounds__(256) void convert_f32_fp8(
    const float* __restrict__ src, unsigned char* __restrict__ dst,
    long n, float scale)
{
    long i = ((long)blockIdx.x * 256 + threadIdx.x) * 8;
    if (i + 8 > n) return;
    f32x8 v = *(const f32x8*)(src + i);
    unsigned char o[8];
    #pragma unroll
    for (int j = 0; j < 8; ++j) {
        __hip_fp8_e4m3 q(v[j] * scale);   // OCP e4m3fn, RNE+sat
        o[j] = q.__x;
    }
    *(uint2*)(dst + i) = *(const uint2*)o;
}

// ----------------------- fp8 K=128 8-phase 256^2 GEMM+LSE ------------------
__global__ __launch_bounds__(512, 2) void gemm_lse(
    const unsigned char* __restrict__ h8,     // [4096][2048] fp8 (x16)
    const unsigned char* __restrict__ W8,     // [seg_rows][2048] fp8 (x64)
    float* __restrict__ part_m, float* __restrict__ part_s, int chunk0)
{
    __shared__ unsigned char A_lds[2][32768];   // [par][256r x 128B] 64 KB
    __shared__ unsigned char B_lds[2][32768];   // 64 KB

    const int tid  = threadIdx.x;
    const int lane = tid & 63;
    const int w    = tid >> 6;       // wave 0..7
    const int wm   = w >> 2;         // 0..1 : token half (128 rows)
    const int wn   = w & 3;          // 0..3 : vocab quarter (64 cols)

    // bijective XCD-aware remap, token-fastest decode
    const int nwg  = gridDim.x;
    const int orig = blockIdx.x;
    const int q8 = nwg >> 3, r8 = nwg & 7;
    const int xcd = orig & 7;
    const int wg  = (xcd < r8 ? xcd * (q8 + 1) : r8 * (q8 + 1) + (xcd - r8) * q8)
                    + (orig >> 3);
    const int tok_blk = wg & (NTB - 1);
    const int voc_blk = wg >> 4;                 // NTB == 16

    const long arow0 = (long)tok_blk * BM;
    const unsigned char* Ab = h8 + arow0 * DIM;
    const unsigned char* Bb = W8 + (long)voc_blk * BN * DIM;

    f32x4 acc[8][4];
    #pragma unroll
    for (int i = 0; i < 8; ++i)
        #pragma unroll
        for (int j = 0; j < 4; ++j)
            acc[i][j] = (f32x4){0.f, 0.f, 0.f, 0.f};

    // ---- staging: tile = 256 rows x 8 chunks(16B); 4 sweeps x 1 gload each.
    // Sweep j covers rows [j*64, j*64+64): r = j*64 + (tid>>3), c = tid&7;
    // src chunk c^(r&7) (j*64 == 0 mod 8) -> LDS[r][c] = G[r][c^(r&7)].
    const long soff = (long)(tid >> 3) * DIM + ((tid & 7) ^ ((tid >> 3) & 7)) * 16;
    const int  sdb  = w * 1024;     // (w*64 chunks)*16B, wave-uniform

#define SW_A(t, j, PD)                                                        \
    gload_lds16(Ab + (t) * BK + soff + (long)(j) * 64 * DIM,                  \
                (char*)&A_lds[PD][0] + sdb + (j) * 8192);
#define SW_B(t, j, PD)                                                        \
    gload_lds16(Bb + (t) * BK + soff + (long)(j) * 64 * DIM,                  \
                (char*)&B_lds[PD][0] + sdb + (j) * 8192);

    // ---- fragment reads: row = base + (lane&15); k-bytes (lane>>4)*32+0..31
    // = chunks (lane>>4)*2 + e, read at chunk ^ (row&7) = ^ (lane&7).
    // 8 distinct chunk-columns per instruction -> r8-verified conflict-free.
    const int lrow = lane & 15;
    const int cxe0 = ((((lane >> 4) * 2) + 0) ^ (lane & 7)) * 16;
    const int cxe1 = ((((lane >> 4) * 2) + 1) ^ (lane & 7)) * 16;

#define LDF(DST, BASE, ROWB)                                                  \
    {                                                                         \
        i32x4 r0_ = *(const i32x4*)((BASE) + (ROWB) + cxe0);                  \
        i32x4 r1_ = *(const i32x4*)((BASE) + (ROWB) + cxe1);                  \
        DST[0] = r0_[0]; DST[1] = r0_[1]; DST[2] = r0_[2]; DST[3] = r0_[3];   \
        DST[4] = r1_[0]; DST[5] = r1_[1]; DST[6] = r1_[2]; DST[7] = r1_[3];   \
    }

#define MFMA8(Q, A0, A1)                                                      \
    __builtin_amdgcn_s_setprio(1);                                            \
    _Pragma("unroll")                                                         \
    for (int nf = 0; nf < 4; ++nf) {                                          \
        acc[(Q) * 2][nf] = __builtin_amdgcn_mfma_scale_f32_16x16x128_f8f6f4(  \
            A0, bfr[nf], acc[(Q) * 2][nf], 0, 0, 0, IDSC, 0, IDSC);           \
        acc[(Q) * 2 + 1][nf] = __builtin_amdgcn_mfma_scale_f32_16x16x128_f8f6f4(\
            A1, bfr[nf], acc[(Q) * 2 + 1][nf], 0, 0, 0, IDSC, 0, IDSC);       \
    }                                                                         \
    __builtin_amdgcn_s_setprio(0);

#define WAITL()                                                               \
    asm volatile("s_waitcnt lgkmcnt(0)" ::: "memory");                        \
    __builtin_amdgcn_sched_barrier(0);

// One K-tile, 4 phases. A(t+1) staged ph0/ph1, B(t+2) staged ph2/ph3.
#define KTILE(P, t)                                                           \
    {                                                                         \
        const char* Ah = (const char*)&A_lds[P][0] + wm * 16384;              \
        const char* Bh = (const char*)&B_lds[P][0] + wn * 8192;               \
        i32x8 bfr[4], a0, a1;                                                 \
        /* ph0: LDB(8) + LDA mf0,1 | stage A0,A1(t+1) */                      \
        LDF(bfr[0], Bh, 0 * 2048 + lrow * 128)                                \
        LDF(bfr[1], Bh, 1 * 2048 + lrow * 128)                                \
        LDF(bfr[2], Bh, 2 * 2048 + lrow * 128)                                \
        LDF(bfr[3], Bh, 3 * 2048 + lrow * 128)                                \
        LDF(a0, Ah, 0 * 2048 + lrow * 128)                                    \
        LDF(a1, Ah, 1 * 2048 + lrow * 128)                                    \
        if ((t) + 1 < NT) { SW_A((t) + 1, 0, (P) ^ 1) SW_A((t) + 1, 1, (P) ^ 1) } \
        bar(); WAITL()                                                        \
        MFMA8(0, a0, a1)                                                      \
        bar();                                                                \
        /* ph1: LDA mf2,3 | stage A2,A3(t+1) */                               \
        LDF(a0, Ah, 2 * 2048 + lrow * 128)                                    \
        LDF(a1, Ah, 3 * 2048 + lrow * 128)                                    \
        if ((t) + 1 < NT) { SW_A((t) + 1, 2, (P) ^ 1) SW_A((t) + 1, 3, (P) ^ 1) } \
        bar(); WAITL()                                                        \
        MFMA8(1, a0, a1)                                                      \
        bar();                                                                \
        /* ph2: LDA mf4,5 | stage B0,B1(t+2) (B[P] reads done in ph0) */      \
        LDF(a0, Ah, 4 * 2048 + lrow * 128)                                    \
        LDF(a1, Ah, 5 * 2048 + lrow * 128)                                    \
        if ((t) + 2 < NT) { SW_B((t) + 2, 0, P) SW_B((t) + 2, 1, P) }         \
        bar(); WAITL()                                                        \
        MFMA8(2, a0, a1)                                                      \
        bar();                                                                \
        /* ph3: LDA mf6,7 | stage B2,B3(t+2) | counted boundary */            \
        LDF(a0, Ah, 6 * 2048 + lrow * 128)                                    \
        LDF(a1, Ah, 7 * 2048 + lrow * 128)                                    \
        if ((t) + 2 < NT) { SW_B((t) + 2, 2, P) SW_B((t) + 2, 3, P) }         \
        bar(); WAITL()                                                        \
        MFMA8(3, a0, a1)                                                      \
        if ((t) < NT - 2) { asm volatile("s_waitcnt vmcnt(4)" ::: "memory"); }\
        else              { asm volatile("s_waitcnt vmcnt(0)" ::: "memory"); }\
        bar();                                                                \
    }

    // prologue: A(0)->A[0], B(0)->B[0], B(1)->B[1]; vmcnt(4): A(0),B(0)
    // landed, B(1) floats (drained by boundary(0)'s vmcnt(4) before t=1).
    SW_A(0, 0, 0) SW_A(0, 1, 0) SW_A(0, 2, 0) SW_A(0, 3, 0)
    SW_B(0, 0, 0) SW_B(0, 1, 0) SW_B(0, 2, 0) SW_B(0, 3, 0)
    SW_B(1, 0, 1) SW_B(1, 1, 1) SW_B(1, 2, 1) SW_B(1, 3, 1)
    asm volatile("s_waitcnt vmcnt(4)" ::: "memory");
    bar();

    for (int t = 0; t < NT; t += 2) {
        KTILE(0, t)
        KTILE(1, t + 1)
    }
#undef KTILE
#undef SW_A
#undef SW_B
#undef LDF
#undef MFMA8
#undef WAITL

    // ---- epilogue: undo input scaling (1/1024), per-token (max, sumexp) ---
    // C frag (shape-determined, verified): row = wm*128 + mf*16 +
    // (lane>>4)*4 + r; col = wn*64 + nf*16 + (lane&15).
    const float INV = 1.0f / 1024.0f;
    float* red_m = (float*)&A_lds[0][0];          // 4 KB
    float* red_s = ((float*)&A_lds[0][0]) + 1024; // 4 KB
    #pragma unroll
    for (int mf = 0; mf < 8; ++mf) {
        #pragma unroll
        for (int r = 0; r < 4; ++r) {
            float v0 = acc[mf][0][r] * INV, v1 = acc[mf][1][r] * INV;
            float v2 = acc[mf][2][r] * INV, v3 = acc[mf][3][r] * INV;
            float mx = fmaxf(fmaxf(v0, v1), fmaxf(v2, v3));
            #pragma unroll
            for (int msk = 1; msk < 16; msk <<= 1)
                mx = fmaxf(mx, __shfl_xor(mx, msk, 64));
            float se = __expf(v0 - mx) + __expf(v1 - mx) +
                       __expf(v2 - mx) + __expf(v3 - mx);
            #pragma unroll
            for (int msk = 1; msk < 16; msk <<= 1)
                se += __shfl_xor(se, msk, 64);
            if ((lane & 15) == 0) {
                const int row = wm * 128 + mf * 16 + (lane >> 4) * 4 + r;
                red_m[row * 4 + wn] = mx;
                red_s[row * 4 + wn] = se;
            }
        }
    }
    __syncthreads();
    if (tid < 256) {
        float M = red_m[tid * 4], S = red_s[tid * 4];
        #pragma unroll
        for (int j = 1; j < 4; ++j) {
            const float m2 = red_m[tid * 4 + j], s2 = red_s[tid * 4 + j];
            const float Mn = fmaxf(M, m2);
            S = S * __expf(M - Mn) + s2 * __expf(m2 - Mn);
            M = Mn;
        }
        part_m[(arow0 + tid) * NCH + chunk0 + voc_blk] = M;
        part_s[(arow0 + tid) * NCH + chunk0 + voc_blk] = S;
    }
}

// ------------------------------------------------------- exact label dot ----
__global__ __launch_bounds__(256) void label_dot(
    const float* __restrict__ h, const float* __restrict__ W,
    const void* __restrict__ labels, float* __restrict__ lab_logit)
{
    bool is64 = true;
    #pragma unroll
    for (int i = 0; i < 8; ++i) {
        long long v = ((const long long*)labels)[i];
        if (v < 0 || v >= VOCAB) is64 = false;
    }
    const int t = blockIdx.x;
    const int lab = is64 ? (int)((const long long*)labels)[t]
                         : ((const int*)labels)[t];
    const float4* hp = (const float4*)(h + (long)t * DIM);
    const float4* wp = (const float4*)(W + (long)lab * DIM);
    float s = 0.f;
    #pragma unroll
    for (int j = 0; j < 2; ++j) {
        const float4 a = hp[threadIdx.x + j * 256];
        const float4 b = wp[threadIdx.x + j * 256];
        s += a.x * b.x + a.y * b.y + a.z * b.z + a.w * b.w;
    }
    #pragma unroll
    for (int msk = 1; msk < 64; msk <<= 1) s += __shfl_xor(s, msk, 64);
    __shared__ float ps[4];
    if ((threadIdx.x & 63) == 0) ps[threadIdx.x >> 6] = s;
    __syncthreads();
    if (threadIdx.x == 0) lab_logit[t] = ps[0] + ps[1] + ps[2] + ps[3];
}

// ---------------------------------------------------- per-token LSE merge ---
__global__ __launch_bounds__(256) void finalize_nll(
    const float* __restrict__ part_m, const float* __restrict__ part_s,
    const float* __restrict__ lab_logit, const float* __restrict__ wts,
    float* __restrict__ wnll)
{
    const int t    = blockIdx.x * 4 + (threadIdx.x >> 6);  // one wave / token
    const int lane = threadIdx.x & 63;
    float m = -3.4e38f, s = 0.f;
    #pragma unroll
    for (int j = 0; j < 4; ++j) {
        const int c = j * 64 + lane;
        const float pm = part_m[(long)t * NCH + c];
        const float ps = part_s[(long)t * NCH + c];
        const float M = fmaxf(m, pm);
        s = s * __expf(m - M) + ps * __expf(pm - M);
        m = M;
    }
    #pragma unroll
    for (int msk = 1; msk < 64; msk <<= 1) {
        const float om = __shfl_xor(m, msk, 64);
        const float os = __shfl_xor(s, msk, 64);
        const float M = fmaxf(m, om);
        s = s * __expf(m - M) + os * __expf(om - M);
        m = M;
    }
    if (lane == 0) {
        const float lse = m + logf(s);
        wnll[t] = wts[t] * (lse - lab_logit[t]);
    }
}

// -------------------------------------------------- deterministic reduce ----
__global__ __launch_bounds__(1024) void final_reduce(
    const float* __restrict__ wnll, const float* __restrict__ wts,
    float* __restrict__ out)
{
    float a = 0.f, b = 0.f;
    #pragma unroll
    for (int j = 0; j < 4; ++j) {
        const int i = threadIdx.x + j * 1024;
        a += wnll[i];
        b += wts[i];
    }
    #pragma unroll
    for (int msk = 1; msk < 64; msk <<= 1) {
        a += __shfl_xor(a, msk, 64);
        b += __shfl_xor(b, msk, 64);
    }
    __shared__ float pa[16], pb[16];
    if ((threadIdx.x & 63) == 0) {
        pa[threadIdx.x >> 6] = a;
        pb[threadIdx.x >> 6] = b;
    }
    __syncthreads();
    if (threadIdx.x == 0) {
        float A = 0.f, B = 0.f;
        #pragma unroll
        for (int i = 0; i < 16; ++i) { A += pa[i]; B += pb[i]; }
        out[0] = A / B;
    }
}

// ----------------------------------------------------------------- launch ---
extern "C" void kernel_launch(void* const* d_in, const int* in_sizes, int n_in,
                              void* d_out, int out_size, void* d_ws, size_t ws_size,
                              hipStream_t stream)
{
    const float* h      = (const float*)d_in[0];
    const void*  labels = d_in[1];
    const float* wts    = (const float*)d_in[2];
    const float* W      = (const float*)d_in[3];
    float* out = (float*)d_out;

    char* ws = (char*)d_ws;
    unsigned char*  h8        = (unsigned char*)(ws);                  //  8 MB
    float*          part_m    = (float*)(ws + (16u << 20));            //  4 MB
    float*          part_s    = (float*)(ws + (24u << 20));            //  4 MB
    float*          lab_logit = (float*)(ws + (32u << 20));            // 16 KB
    float*          wnll      = (float*)(ws + (32u << 20) + 16384);    // 16 KB
    unsigned char*  wseg      = (unsigned char*)(ws + (32u << 20) + 32768);
    const size_t base = (size_t)(32u << 20) + 32768;

    long segmax = 0;
    if (ws_size > base) segmax = (long)((ws_size - base) / (size_t)DIM);
    segmax &= ~255L;
    if (segmax > VOCAB) segmax = VOCAB;
    if (segmax < 256)   segmax = 256;   // require ws_size >= ~33.5 MB

    // 0) h -> fp8 (x16)
    convert_f32_fp8<<<(N_TOK * DIM) / (256 * 8), 256, 0, stream>>>(
        h, h8, (long)N_TOK * DIM, 16.0f);

    // 1) segmented W -> fp8 (x64) + fused GEMM/LSE partials
    for (long v0 = 0; v0 < VOCAB; v0 += segmax) {
        const long rows = (VOCAB - v0) < segmax ? (VOCAB - v0) : segmax;
        convert_f32_fp8<<<(int)(rows * DIM / (256 * 8)), 256, 0, stream>>>(
            W + v0 * DIM, wseg, rows * (long)DIM, 64.0f);
        const int nwg = (int)(rows / BM) * NTB;
        gemm_lse<<<nwg, 512, 0, stream>>>(h8, wseg, part_m, part_s,
                                          (int)(v0 / BN));
    }

    // 2) exact label logits (fp32)
    label_dot<<<N_TOK, 256, 0, stream>>>(h, W, labels, lab_logit);

    // 3) per-token LSE merge -> w*nll
    finalize_nll<<<N_TOK / 4, 256, 0, stream>>>(part_m, part_s, lab_logit,
                                                wts, wnll);

    // 4) weighted mean
    final_reduce<<<1, 1024, 0, stream>>>(wnll, wts, out);
}

// Round 13
// 988.486 us; speedup vs baseline: 2.9968x; 2.9968x over previous
//
#include <hip/hip_runtime.h>
#include <hip/hip_fp8.h>

// ---------------------------------------------------------------------------
// FusedSparseLMHead: weighted-mean CE over h @ W^T without materializing logits.
//   h: [4096, 2048] f32, W: [65536, 2048] f32, labels: [4096] int, w: [4096] f32
// Round 13: NON-scaled fp8 e4m3 GEMM (mfma_f32_16x16x32_fp8_fp8, i64 ops).
//   fp8 halves LDS/staging bytes per k; K-tile = 128 fp8 (= r11 byte geometry:
//   128-B rows, 8 chunks, c^(r&7) both-sides swizzle, measured 0-conflict).
//   Convert kernels write a k-INTERLEAVED layout (within each 128-k group:
//   new = s*32 + kk*8 + j for orig k = kk*32 + s*8 + j) so each lane's four
//   8-B instruction operands sit in two contiguous b128 reads (r12 cxe addrs).
//   Schedule = r11's verified 8-phase/2-K-tile: A(t+1) staged ph0/ph1,
//   B(t+2) ph2/ph3, boundary vmcnt(4) counted (queue proof verbatim).
//   Inputs pre-scaled h*16, W*64 (no e4m3 denormals); epilogue * 1/1024.
// ---------------------------------------------------------------------------

typedef __attribute__((ext_vector_type(4)))  float f32x4;
typedef __attribute__((ext_vector_type(8)))  float f32x8;
typedef __attribute__((ext_vector_type(4)))  int   i32x4;
typedef long long i64;

#define N_TOK 4096
#define DIM   2048          // fp8 bytes per row
#define VOCAB 65536
#define BM    256
#define BN    256
#define BK    128           // fp8 elements per K-tile
#define NT    (DIM / BK)    // 16 K-tiles
#define NCH   (VOCAB / BN)  // 256 vocab chunks
#define NTB   (N_TOK / BM)  // 16 token blocks

__device__ __forceinline__ void gload_lds16(const void* g, void* l) {
    __builtin_amdgcn_global_load_lds(
        (const __attribute__((address_space(1))) void*)g,
        (__attribute__((address_space(3))) void*)l, 16, 0, 0);
}

__device__ __forceinline__ void bar() {
    asm volatile("" ::: "memory");
    __builtin_amdgcn_s_barrier();
    asm volatile("" ::: "memory");
}

__device__ __forceinline__ i64 pack2(int lo, int hi) {
    union { int i[2]; i64 l; } u;
    u.i[0] = lo; u.i[1] = hi;
    return u.l;
}

// --------------------------------------- convert fp8 + k-interleave permute -
__global__ __launch_bounds__(256) void convert_f32_fp8(
    const float* __restrict__ src, unsigned char* __restrict__ dst,
    long n, float scale)
{
    long i = ((long)blockIdx.x * 256 + threadIdx.x) * 8;
    if (i + 8 > n) return;
    f32x8 v = *(const f32x8*)(src + i);
    unsigned char o[8];
    #pragma unroll
    for (int j = 0; j < 8; ++j) {
        __hip_fp8_e4m3 q(v[j] * scale);   // OCP e4m3fn, RNE+sat
        o[j] = q.__x;
    }
    // k-interleave within the 128-k group: orig k = kk*32 + s*8 + j
    // -> new = s*32 + kk*8 + j. All 8 elems share (s, kk).
    const long base = i & ~127L;
    const long s    = (i >> 3) & 3;
    const long kk   = (i >> 5) & 3;
    *(uint2*)(dst + base + s * 32 + kk * 8) = *(const uint2*)o;
}

// ----------------------- fp8 16x16x32 8-phase 256^2 GEMM+LSE ---------------
__global__ __launch_bounds__(512, 2) void gemm_lse(
    const unsigned char* __restrict__ h8,     // [4096][2048] fp8 perm (x16)
    const unsigned char* __restrict__ W8,     // [seg_rows][2048] fp8 perm (x64)
    float* __restrict__ part_m, float* __restrict__ part_s, int chunk0)
{
    __shared__ unsigned char A_lds[2][32768];   // [par][256r x 128B] 64 KB
    __shared__ unsigned char B_lds[2][32768];   // 64 KB

    const int tid  = threadIdx.x;
    const int lane = tid & 63;
    const int w    = tid >> 6;       // wave 0..7
    const int wm   = w >> 2;         // 0..1 : token half (128 rows)
    const int wn   = w & 3;          // 0..3 : vocab quarter (64 cols)

    // bijective XCD-aware remap, token-fastest decode
    const int nwg  = gridDim.x;
    const int orig = blockIdx.x;
    const int q8 = nwg >> 3, r8 = nwg & 7;
    const int xcd = orig & 7;
    const int wg  = (xcd < r8 ? xcd * (q8 + 1) : r8 * (q8 + 1) + (xcd - r8) * q8)
                    + (orig >> 3);
    const int tok_blk = wg & (NTB - 1);
    const int voc_blk = wg >> 4;                 // NTB == 16

    const long arow0 = (long)tok_blk * BM;
    const unsigned char* Ab = h8 + arow0 * DIM;
    const unsigned char* Bb = W8 + (long)voc_blk * BN * DIM;

    f32x4 acc[8][4];
    #pragma unroll
    for (int i = 0; i < 8; ++i)
        #pragma unroll
        for (int j = 0; j < 4; ++j)
            acc[i][j] = (f32x4){0.f, 0.f, 0.f, 0.f};

    // ---- staging (r12-proven dims): tile = 256r x 8 chunks(16B); 4 sweeps.
    // Sweep j rows [j*64, j*64+64): r = j*64 + (tid>>3), c = tid&7;
    // src chunk c^(r&7) -> LDS[r][c] = G[r][c^(r&7)] (linear dest).
    const long soff = (long)(tid >> 3) * DIM + ((tid & 7) ^ ((tid >> 3) & 7)) * 16;
    const int  sdb  = w * 1024;     // wave-uniform dest base (bytes)

#define SW_A(t, j, PD)                                                        \
    gload_lds16(Ab + (t) * BK + soff + (long)(j) * 64 * DIM,                  \
                (char*)&A_lds[PD][0] + sdb + (j) * 8192);
#define SW_B(t, j, PD)                                                        \
    gload_lds16(Bb + (t) * BK + soff + (long)(j) * 64 * DIM,                  \
                (char*)&B_lds[PD][0] + sdb + (j) * 8192);

    // ---- fragment reads (r11-measured 0-conflict shape): row = base+lrow,
    // chunks (lane>>4)*2 + e read at chunk ^ (lane&7); native b128 loads.
    const int lrow = lane & 15;
    const int cxe0 = ((((lane >> 4) * 2) + 0) ^ (lane & 7)) * 16;
    const int cxe1 = ((((lane >> 4) * 2) + 1) ^ (lane & 7)) * 16;

#define LDF2(D, BASE, ROWB)                                                   \
    D[0] = *(const i32x4*)((BASE) + (ROWB) + cxe0);                           \
    D[1] = *(const i32x4*)((BASE) + (ROWB) + cxe1);

    // 32 MFMA per phase: kk slice p = kk>>1 (which b128), q2 = (kk&1)*2.
#define MFMA32(Q, A0, A1)                                                     \
    __builtin_amdgcn_s_setprio(1);                                            \
    _Pragma("unroll")                                                         \
    for (int kk = 0; kk < 4; ++kk) {                                          \
        const int p_ = kk >> 1, q2_ = (kk & 1) * 2;                           \
        const i64 avx = pack2(A0[p_][q2_], A0[p_][q2_ + 1]);                  \
        const i64 avy = pack2(A1[p_][q2_], A1[p_][q2_ + 1]);                  \
        _Pragma("unroll")                                                     \
        for (int nf = 0; nf < 4; ++nf) {                                      \
            const i64 bv = pack2(bR[nf][p_][q2_], bR[nf][p_][q2_ + 1]);       \
            acc[(Q) * 2][nf] = __builtin_amdgcn_mfma_f32_16x16x32_fp8_fp8(    \
                avx, bv, acc[(Q) * 2][nf], 0, 0, 0);                          \
            acc[(Q) * 2 + 1][nf] = __builtin_amdgcn_mfma_f32_16x16x32_fp8_fp8(\
                avy, bv, acc[(Q) * 2 + 1][nf], 0, 0, 0);                      \
        }                                                                     \
    }                                                                         \
    __builtin_amdgcn_s_setprio(0);

#define WAITL()                                                               \
    asm volatile("s_waitcnt lgkmcnt(0)" ::: "memory");                        \
    __builtin_amdgcn_sched_barrier(0);

// One K-tile(128), 4 phases. A(t+1) staged ph0/ph1, B(t+2) ph2/ph3.
#define KTILE(P, t)                                                           \
    {                                                                         \
        const char* Ah = (const char*)&A_lds[P][0] + wm * 16384;              \
        const char* Bh = (const char*)&B_lds[P][0] + wn * 8192;               \
        i32x4 bR[4][2], aX[2], aY[2];                                         \
        /* ph0: LDB(8 b128) + LDA mf0,1 | stage A sweeps 0,1 (t+1) */         \
        LDF2(bR[0], Bh, 0 * 2048 + lrow * 128)                                \
        LDF2(bR[1], Bh, 1 * 2048 + lrow * 128)                                \
        LDF2(bR[2], Bh, 2 * 2048 + lrow * 128)                                \
        LDF2(bR[3], Bh, 3 * 2048 + lrow * 128)                                \
        LDF2(aX, Ah, 0 * 2048 + lrow * 128)                                   \
        LDF2(aY, Ah, 1 * 2048 + lrow * 128)                                   \
        if ((t) + 1 < NT) { SW_A((t) + 1, 0, (P) ^ 1) SW_A((t) + 1, 1, (P) ^ 1) } \
        bar(); WAITL()                                                        \
        MFMA32(0, aX, aY)                                                     \
        bar();                                                                \
        /* ph1: LDA mf2,3 | stage A sweeps 2,3 (t+1) */                       \
        LDF2(aX, Ah, 2 * 2048 + lrow * 128)                                   \
        LDF2(aY, Ah, 3 * 2048 + lrow * 128)                                   \
        if ((t) + 1 < NT) { SW_A((t) + 1, 2, (P) ^ 1) SW_A((t) + 1, 3, (P) ^ 1) } \
        bar(); WAITL()                                                        \
        MFMA32(1, aX, aY)                                                     \
        bar();                                                                \
        /* ph2: LDA mf4,5 | stage B sweeps 0,1 (t+2) (B[P] reads done ph0) */ \
        LDF2(aX, Ah, 4 * 2048 + lrow * 128)                                   \
        LDF2(aY, Ah, 5 * 2048 + lrow * 128)                                   \
        if ((t) + 2 < NT) { SW_B((t) + 2, 0, P) SW_B((t) + 2, 1, P) }         \
        bar(); WAITL()                                                        \
        MFMA32(2, aX, aY)                                                     \
        bar();                                                                \
        /* ph3: LDA mf6,7 | stage B sweeps 2,3 (t+2) | counted boundary */    \
        LDF2(aX, Ah, 6 * 2048 + lrow * 128)                                   \
        LDF2(aY, Ah, 7 * 2048 + lrow * 128)                                   \
        if ((t) + 2 < NT) { SW_B((t) + 2, 2, P) SW_B((t) + 2, 3, P) }         \
        bar(); WAITL()                                                        \
        MFMA32(3, aX, aY)                                                     \
        if ((t) < NT - 2) { asm volatile("s_waitcnt vmcnt(4)" ::: "memory"); }\
        else              { asm volatile("s_waitcnt vmcnt(0)" ::: "memory"); }\
        bar();                                                                \
    }

    // prologue: A(0)->A[0], B(0)->B[0], B(1)->B[1]; vmcnt(4): A(0),B(0)
    // landed, B(1) floats (drained by boundary(0)'s vmcnt(4) before t=1).
    SW_A(0, 0, 0) SW_A(0, 1, 0) SW_A(0, 2, 0) SW_A(0, 3, 0)
    SW_B(0, 0, 0) SW_B(0, 1, 0) SW_B(0, 2, 0) SW_B(0, 3, 0)
    SW_B(1, 0, 1) SW_B(1, 1, 1) SW_B(1, 2, 1) SW_B(1, 3, 1)
    asm volatile("s_waitcnt vmcnt(4)" ::: "memory");
    bar();

    for (int t = 0; t < NT; t += 2) {
        KTILE(0, t)
        KTILE(1, t + 1)
    }
#undef KTILE
#undef SW_A
#undef SW_B
#undef LDF2
#undef MFMA32
#undef WAITL

    // ---- epilogue: undo input scaling (1/1024), per-token (max, sumexp) ---
    // C frag (shape-determined, r12-verified): row = wm*128 + mf*16 +
    // (lane>>4)*4 + r; col = wn*64 + nf*16 + (lane&15).
    const float INV = 1.0f / 1024.0f;
    float* red_m = (float*)&A_lds[0][0];          // 4 KB
    float* red_s = ((float*)&A_lds[0][0]) + 1024; // 4 KB
    #pragma unroll
    for (int mf = 0; mf < 8; ++mf) {
        #pragma unroll
        for (int r = 0; r < 4; ++r) {
            float v0 = acc[mf][0][r] * INV, v1 = acc[mf][1][r] * INV;
            float v2 = acc[mf][2][r] * INV, v3 = acc[mf][3][r] * INV;
            float mx = fmaxf(fmaxf(v0, v1), fmaxf(v2, v3));
            #pragma unroll
            for (int msk = 1; msk < 16; msk <<= 1)
                mx = fmaxf(mx, __shfl_xor(mx, msk, 64));
            float se = __expf(v0 - mx) + __expf(v1 - mx) +
                       __expf(v2 - mx) + __expf(v3 - mx);
            #pragma unroll
            for (int msk = 1; msk < 16; msk <<= 1)
                se += __shfl_xor(se, msk, 64);
            if ((lane & 15) == 0) {
                const int row = wm * 128 + mf * 16 + (lane >> 4) * 4 + r;
                red_m[row * 4 + wn] = mx;
                red_s[row * 4 + wn] = se;
            }
        }
    }
    __syncthreads();
    if (tid < 256) {
        float M = red_m[tid * 4], S = red_s[tid * 4];
        #pragma unroll
        for (int j = 1; j < 4; ++j) {
            const float m2 = red_m[tid * 4 + j], s2 = red_s[tid * 4 + j];
            const float Mn = fmaxf(M, m2);
            S = S * __expf(M - Mn) + s2 * __expf(m2 - Mn);
            M = Mn;
        }
        part_m[(arow0 + tid) * NCH + chunk0 + voc_blk] = M;
        part_s[(arow0 + tid) * NCH + chunk0 + voc_blk] = S;
    }
}

// ------------------------------------------------------- exact label dot ----
__global__ __launch_bounds__(256) void label_dot(
    const float* __restrict__ h, const float* __restrict__ W,
    const void* __restrict__ labels, float* __restrict__ lab_logit)
{
    bool is64 = true;
    #pragma unroll
    for (int i = 0; i < 8; ++i) {
        long long v = ((const long long*)labels)[i];
        if (v < 0 || v >= VOCAB) is64 = false;
    }
    const int t = blockIdx.x;
    const int lab = is64 ? (int)((const long long*)labels)[t]
                         : ((const int*)labels)[t];
    const float4* hp = (const float4*)(h + (long)t * DIM);
    const float4* wp = (const float4*)(W + (long)lab * DIM);
    float s = 0.f;
    #pragma unroll
    for (int j = 0; j < 2; ++j) {
        const float4 a = hp[threadIdx.x + j * 256];
        const float4 b = wp[threadIdx.x + j * 256];
        s += a.x * b.x + a.y * b.y + a.z * b.z + a.w * b.w;
    }
    #pragma unroll
    for (int msk = 1; msk < 64; msk <<= 1) s += __shfl_xor(s, msk, 64);
    __shared__ float ps[4];
    if ((threadIdx.x & 63) == 0) ps[threadIdx.x >> 6] = s;
    __syncthreads();
    if (threadIdx.x == 0) lab_logit[t] = ps[0] + ps[1] + ps[2] + ps[3];
}

// ---------------------------------------------------- per-token LSE merge ---
__global__ __launch_bounds__(256) void finalize_nll(
    const float* __restrict__ part_m, const float* __restrict__ part_s,
    const float* __restrict__ lab_logit, const float* __restrict__ wts,
    float* __restrict__ wnll)
{
    const int t    = blockIdx.x * 4 + (threadIdx.x >> 6);  // one wave / token
    const int lane = threadIdx.x & 63;
    float m = -3.4e38f, s = 0.f;
    #pragma unroll
    for (int j = 0; j < 4; ++j) {
        const int c = j * 64 + lane;
        const float pm = part_m[(long)t * NCH + c];
        const float ps = part_s[(long)t * NCH + c];
        const float M = fmaxf(m, pm);
        s = s * __expf(m - M) + ps * __expf(pm - M);
        m = M;
    }
    #pragma unroll
    for (int msk = 1; msk < 64; msk <<= 1) {
        const float om = __shfl_xor(m, msk, 64);
        const float os = __shfl_xor(s, msk, 64);
        const float M = fmaxf(m, om);
        s = s * __expf(m - M) + os * __expf(om - M);
        m = M;
    }
    if (lane == 0) {
        const float lse = m + logf(s);
        wnll[t] = wts[t] * (lse - lab_logit[t]);
    }
}

// -------------------------------------------------- deterministic reduce ----
__global__ __launch_bounds__(1024) void final_reduce(
    const float* __restrict__ wnll, const float* __restrict__ wts,
    float* __restrict__ out)
{
    float a = 0.f, b = 0.f;
    #pragma unroll
    for (int j = 0; j < 4; ++j) {
        const int i = threadIdx.x + j * 1024;
        a += wnll[i];
        b += wts[i];
    }
    #pragma unroll
    for (int msk = 1; msk < 64; msk <<= 1) {
        a += __shfl_xor(a, msk, 64);
        b += __shfl_xor(b, msk, 64);
    }
    __shared__ float pa[16], pb[16];
    if ((threadIdx.x & 63) == 0) {
        pa[threadIdx.x >> 6] = a;
        pb[threadIdx.x >> 6] = b;
    }
    __syncthreads();
    if (threadIdx.x == 0) {
        float A = 0.f, B = 0.f;
        #pragma unroll
        for (int i = 0; i < 16; ++i) { A += pa[i]; B += pb[i]; }
        out[0] = A / B;
    }
}

// ----------------------------------------------------------------- launch ---
extern "C" void kernel_launch(void* const* d_in, const int* in_sizes, int n_in,
                              void* d_out, int out_size, void* d_ws, size_t ws_size,
                              hipStream_t stream)
{
    const float* h      = (const float*)d_in[0];
    const void*  labels = d_in[1];
    const float* wts    = (const float*)d_in[2];
    const float* W      = (const float*)d_in[3];
    float* out = (float*)d_out;

    char* ws = (char*)d_ws;
    unsigned char*  h8        = (unsigned char*)(ws);                  //  8 MB
    float*          part_m    = (float*)(ws + (16u << 20));            //  4 MB
    float*          part_s    = (float*)(ws + (24u << 20));            //  4 MB
    float*          lab_logit = (float*)(ws + (32u << 20));            // 16 KB
    float*          wnll      = (float*)(ws + (32u << 20) + 16384);    // 16 KB
    unsigned char*  wseg      = (unsigned char*)(ws + (32u << 20) + 32768);
    const size_t base = (size_t)(32u << 20) + 32768;

    long segmax = 0;
    if (ws_size > base) segmax = (long)((ws_size - base) / (size_t)DIM);
    segmax &= ~255L;
    if (segmax > VOCAB) segmax = VOCAB;
    if (segmax < 256)   segmax = 256;   // require ws_size >= ~33.5 MB

    // 0) h -> fp8 (x16), k-interleaved
    convert_f32_fp8<<<(N_TOK * DIM) / (256 * 8), 256, 0, stream>>>(
        h, h8, (long)N_TOK * DIM, 16.0f);

    // 1) segmented W -> fp8 (x64, k-interleaved) + fused GEMM/LSE partials
    for (long v0 = 0; v0 < VOCAB; v0 += segmax) {
        const long rows = (VOCAB - v0) < segmax ? (VOCAB - v0) : segmax;
        convert_f32_fp8<<<(int)(rows * DIM / (256 * 8)), 256, 0, stream>>>(
            W + v0 * DIM, wseg, rows * (long)DIM, 64.0f);
        const int nwg = (int)(rows / BM) * NTB;
        gemm_lse<<<nwg, 512, 0, stream>>>(h8, wseg, part_m, part_s,
                                          (int)(v0 / BN));
    }

    // 2) exact label logits (fp32)
    label_dot<<<N_TOK, 256, 0, stream>>>(h, W, labels, lab_logit);

    // 3) per-token LSE merge -> w*nll
    finalize_nll<<<N_TOK / 4, 256, 0, stream>>>(part_m, part_s, lab_logit,
                                                wts, wnll);

    // 4) weighted mean
    final_reduce<<<1, 1024, 0, stream>>>(wnll, wts, out);
}

// Round 14
// 977.669 us; speedup vs baseline: 3.0300x; 1.0111x over previous
//
#include <hip/hip_runtime.h>
#include <hip/hip_fp8.h>

// ---------------------------------------------------------------------------
// FusedSparseLMHead: weighted-mean CE over h @ W^T without materializing logits.
//   h: [4096, 2048] f32, W: [65536, 2048] f32, labels: [4096] int, w: [4096] f32
// Round 14: r13 fp8 skeleton with (1) bit_cast i64x2 sub-register operand
//   slicing (kills ~770 cyc/K-tile of pack2 v_movs) and (2) 2 phases +
//   3 barriers per K-tile (was 4 phases / 8 barriers).
//   ph0: LDB(8)+LDA mf0-3(8) | stage A(t+1) x4 | bar1 | lgkm0 | 64 MFMA
//   ph1: LDA mf4-7(8) | bar2 | stage B(t+2) x4 | lgkm0 | 64 MFMA
//        | vmcnt(4) | bar3
//   Safety: stage-B after bar2 (every wave's ph0 B-reads completed at its own
//   lgkm0 before bar2); stage-A targets A[P^1] whose readers passed bar3(t-1);
//   boundary vmcnt(4) forces A(t+1)+older (B(t+2)'s 4 float) -- r13 proof.
//   Numerics (r12/r13-verified): h*16, W*64 pre-scale; epilogue *1/1024;
//   k-interleaved convert so operands are contiguous b128 pairs.
// ---------------------------------------------------------------------------

typedef __attribute__((ext_vector_type(4)))  float f32x4;
typedef __attribute__((ext_vector_type(8)))  float f32x8;
typedef __attribute__((ext_vector_type(4)))  int   i32x4;
typedef __attribute__((ext_vector_type(2)))  long long i64x2;
typedef long long i64;

#define N_TOK 4096
#define DIM   2048          // fp8 bytes per row
#define VOCAB 65536
#define BM    256
#define BN    256
#define BK    128           // fp8 elements per K-tile
#define NT    (DIM / BK)    // 16 K-tiles
#define NCH   (VOCAB / BN)  // 256 vocab chunks
#define NTB   (N_TOK / BM)  // 16 token blocks

__device__ __forceinline__ void gload_lds16(const void* g, void* l) {
    __builtin_amdgcn_global_load_lds(
        (const __attribute__((address_space(1))) void*)g,
        (__attribute__((address_space(3))) void*)l, 16, 0, 0);
}

__device__ __forceinline__ void bar() {
    asm volatile("" ::: "memory");
    __builtin_amdgcn_s_barrier();
    asm volatile("" ::: "memory");
}

// --------------------------------------- convert fp8 + k-interleave permute -
__global__ __launch_bounds__(256) void convert_f32_fp8(
    const float* __restrict__ src, unsigned char* __restrict__ dst,
    long n, float scale)
{
    long i = ((long)blockIdx.x * 256 + threadIdx.x) * 8;
    if (i + 8 > n) return;
    f32x8 v = *(const f32x8*)(src + i);
    unsigned char o[8];
    #pragma unroll
    for (int j = 0; j < 8; ++j) {
        __hip_fp8_e4m3 q(v[j] * scale);   // OCP e4m3fn, RNE+sat
        o[j] = q.__x;
    }
    // k-interleave within the 128-k group: orig k = kk*32 + s*8 + j
    // -> new = s*32 + kk*8 + j. All 8 elems share (s, kk).
    const long base = i & ~127L;
    const long s    = (i >> 3) & 3;
    const long kk   = (i >> 5) & 3;
    *(uint2*)(dst + base + s * 32 + kk * 8) = *(const uint2*)o;
}

// ------------------- fp8 16x16x32 2-phase/3-barrier 256^2 GEMM+LSE ---------
__global__ __launch_bounds__(512, 2) void gemm_lse(
    const unsigned char* __restrict__ h8,     // [4096][2048] fp8 perm (x16)
    const unsigned char* __restrict__ W8,     // [seg_rows][2048] fp8 perm (x64)
    float* __restrict__ part_m, float* __restrict__ part_s, int chunk0)
{
    __shared__ unsigned char A_lds[2][32768];   // [par][256r x 128B] 64 KB
    __shared__ unsigned char B_lds[2][32768];   // 64 KB

    const int tid  = threadIdx.x;
    const int lane = tid & 63;
    const int w    = tid >> 6;       // wave 0..7
    const int wm   = w >> 2;         // 0..1 : token half (128 rows)
    const int wn   = w & 3;          // 0..3 : vocab quarter (64 cols)

    // bijective XCD-aware remap, token-fastest decode
    const int nwg  = gridDim.x;
    const int orig = blockIdx.x;
    const int q8 = nwg >> 3, r8 = nwg & 7;
    const int xcd = orig & 7;
    const int wg  = (xcd < r8 ? xcd * (q8 + 1) : r8 * (q8 + 1) + (xcd - r8) * q8)
                    + (orig >> 3);
    const int tok_blk = wg & (NTB - 1);
    const int voc_blk = wg >> 4;                 // NTB == 16

    const long arow0 = (long)tok_blk * BM;
    const unsigned char* Ab = h8 + arow0 * DIM;
    const unsigned char* Bb = W8 + (long)voc_blk * BN * DIM;

    f32x4 acc[8][4];
    #pragma unroll
    for (int i = 0; i < 8; ++i)
        #pragma unroll
        for (int j = 0; j < 4; ++j)
            acc[i][j] = (f32x4){0.f, 0.f, 0.f, 0.f};

    // ---- staging (r12/r13-proven): tile = 256r x 8 chunks(16B); 4 sweeps.
    // Sweep j rows [j*64, j*64+64): r = j*64 + (tid>>3), c = tid&7;
    // src chunk c^(r&7) -> LDS[r][c] = G[r][c^(r&7)] (linear dest).
    const long soff = (long)(tid >> 3) * DIM + ((tid & 7) ^ ((tid >> 3) & 7)) * 16;
    const int  sdb  = w * 1024;     // wave-uniform dest base (bytes)

#define SW_A(t, j, PD)                                                        \
    gload_lds16(Ab + (t) * BK + soff + (long)(j) * 64 * DIM,                  \
                (char*)&A_lds[PD][0] + sdb + (j) * 8192);
#define SW_B(t, j, PD)                                                        \
    gload_lds16(Bb + (t) * BK + soff + (long)(j) * 64 * DIM,                  \
                (char*)&B_lds[PD][0] + sdb + (j) * 8192);

    // ---- fragment reads (r13 addressing): row = base+lrow, chunks
    // (lane>>4)*2 + e read at chunk ^ (lane&7); native b128 loads.
    const int lrow = lane & 15;
    const int cxe0 = ((((lane >> 4) * 2) + 0) ^ (lane & 7)) * 16;
    const int cxe1 = ((((lane >> 4) * 2) + 1) ^ (lane & 7)) * 16;

#define LDF2(D, BASE, ROWB)                                                   \
    D[0] = *(const i32x4*)((BASE) + (ROWB) + cxe0);                           \
    D[1] = *(const i32x4*)((BASE) + (ROWB) + cxe1);

    // i64 operand slice kk of a row's two b128s: even-aligned subreg pair.
#define OPK(R, KK) (__builtin_bit_cast(i64x2, (R)[(KK) >> 1])[(KK) & 1])

    // 64 MFMA: 4 kk x 4 m x 4 nf over acc[MB..MB+3].
#define MFMA64(MB, AR)                                                        \
    __builtin_amdgcn_s_setprio(1);                                            \
    _Pragma("unroll")                                                         \
    for (int kk = 0; kk < 4; ++kk)                                            \
        _Pragma("unroll")                                                     \
        for (int m = 0; m < 4; ++m) {                                         \
            const i64 av = OPK(AR[m], kk);                                    \
            _Pragma("unroll")                                                 \
            for (int nf = 0; nf < 4; ++nf)                                    \
                acc[(MB) + m][nf] = __builtin_amdgcn_mfma_f32_16x16x32_fp8_fp8(\
                    av, OPK(bR[nf], kk), acc[(MB) + m][nf], 0, 0, 0);         \
        }                                                                     \
    __builtin_amdgcn_s_setprio(0);

#define WAITL()                                                               \
    asm volatile("s_waitcnt lgkmcnt(0)" ::: "memory");                        \
    __builtin_amdgcn_sched_barrier(0);

// One K-tile(128): 2 phases, 3 barriers.
#define KTILE(P, t)                                                           \
    {                                                                         \
        const char* Ah = (const char*)&A_lds[P][0] + wm * 16384;              \
        const char* Bh = (const char*)&B_lds[P][0] + wn * 8192;               \
        i32x4 bR[4][2], aR[4][2];                                             \
        /* ph0: LDB(8) + LDA mf0-3(8) | stage A(t+1) sweeps 0-3 */            \
        LDF2(bR[0], Bh, 0 * 2048 + lrow * 128)                                \
        LDF2(bR[1], Bh, 1 * 2048 + lrow * 128)                                \
        LDF2(bR[2], Bh, 2 * 2048 + lrow * 128)                                \
        LDF2(bR[3], Bh, 3 * 2048 + lrow * 128)                                \
        LDF2(aR[0], Ah, 0 * 2048 + lrow * 128)                                \
        LDF2(aR[1], Ah, 1 * 2048 + lrow * 128)                                \
        LDF2(aR[2], Ah, 2 * 2048 + lrow * 128)                                \
        LDF2(aR[3], Ah, 3 * 2048 + lrow * 128)                                \
        if ((t) + 1 < NT) {                                                   \
            SW_A((t) + 1, 0, (P) ^ 1) SW_A((t) + 1, 1, (P) ^ 1)               \
            SW_A((t) + 1, 2, (P) ^ 1) SW_A((t) + 1, 3, (P) ^ 1)               \
        }                                                                     \
        bar(); WAITL()                                                        \
        MFMA64(0, aR)                                                         \
        /* ph1: LDA mf4-7(8) | bar2 | stage B(t+2) | lgkm0 | 64 MFMA */       \
        LDF2(aR[0], Ah, 4 * 2048 + lrow * 128)                                \
        LDF2(aR[1], Ah, 5 * 2048 + lrow * 128)                                \
        LDF2(aR[2], Ah, 6 * 2048 + lrow * 128)                                \
        LDF2(aR[3], Ah, 7 * 2048 + lrow * 128)                                \
        bar();                                                                \
        if ((t) + 2 < NT) {                                                   \
            SW_B((t) + 2, 0, P) SW_B((t) + 2, 1, P)                           \
            SW_B((t) + 2, 2, P) SW_B((t) + 2, 3, P)                           \
        }                                                                     \
        WAITL()                                                               \
        MFMA64(4, aR)                                                         \
        if ((t) < NT - 2) { asm volatile("s_waitcnt vmcnt(4)" ::: "memory"); }\
        else              { asm volatile("s_waitcnt vmcnt(0)" ::: "memory"); }\
        bar();                                                                \
    }

    // prologue: A(0)->A[0], B(0)->B[0], B(1)->B[1]; vmcnt(4): A(0),B(0)
    // landed, B(1) floats (drained by boundary(0)'s vmcnt(4) before t=1).
    SW_A(0, 0, 0) SW_A(0, 1, 0) SW_A(0, 2, 0) SW_A(0, 3, 0)
    SW_B(0, 0, 0) SW_B(0, 1, 0) SW_B(0, 2, 0) SW_B(0, 3, 0)
    SW_B(1, 0, 1) SW_B(1, 1, 1) SW_B(1, 2, 1) SW_B(1, 3, 1)
    asm volatile("s_waitcnt vmcnt(4)" ::: "memory");
    bar();

    for (int t = 0; t < NT; t += 2) {
        KTILE(0, t)
        KTILE(1, t + 1)
    }
#undef KTILE
#undef SW_A
#undef SW_B
#undef LDF2
#undef OPK
#undef MFMA64
#undef WAITL

    // ---- epilogue: undo input scaling (1/1024), per-token (max, sumexp) ---
    // C frag (shape-determined, r12/r13-verified): row = wm*128 + mf*16 +
    // (lane>>4)*4 + r; col = wn*64 + nf*16 + (lane&15).
    const float INV = 1.0f / 1024.0f;
    float* red_m = (float*)&A_lds[0][0];          // 4 KB
    float* red_s = ((float*)&A_lds[0][0]) + 1024; // 4 KB
    #pragma unroll
    for (int mf = 0; mf < 8; ++mf) {
        #pragma unroll
        for (int r = 0; r < 4; ++r) {
            float v0 = acc[mf][0][r] * INV, v1 = acc[mf][1][r] * INV;
            float v2 = acc[mf][2][r] * INV, v3 = acc[mf][3][r] * INV;
            float mx = fmaxf(fmaxf(v0, v1), fmaxf(v2, v3));
            #pragma unroll
            for (int msk = 1; msk < 16; msk <<= 1)
                mx = fmaxf(mx, __shfl_xor(mx, msk, 64));
            float se = __expf(v0 - mx) + __expf(v1 - mx) +
                       __expf(v2 - mx) + __expf(v3 - mx);
            #pragma unroll
            for (int msk = 1; msk < 16; msk <<= 1)
                se += __shfl_xor(se, msk, 64);
            if ((lane & 15) == 0) {
                const int row = wm * 128 + mf * 16 + (lane >> 4) * 4 + r;
                red_m[row * 4 + wn] = mx;
                red_s[row * 4 + wn] = se;
            }
        }
    }
    __syncthreads();
    if (tid < 256) {
        float M = red_m[tid * 4], S = red_s[tid * 4];
        #pragma unroll
        for (int j = 1; j < 4; ++j) {
            const float m2 = red_m[tid * 4 + j], s2 = red_s[tid * 4 + j];
            const float Mn = fmaxf(M, m2);
            S = S * __expf(M - Mn) + s2 * __expf(m2 - Mn);
            M = Mn;
        }
        part_m[(arow0 + tid) * NCH + chunk0 + voc_blk] = M;
        part_s[(arow0 + tid) * NCH + chunk0 + voc_blk] = S;
    }
}

// ------------------------------------------------------- exact label dot ----
__global__ __launch_bounds__(256) void label_dot(
    const float* __restrict__ h, const float* __restrict__ W,
    const void* __restrict__ labels, float* __restrict__ lab_logit)
{
    bool is64 = true;
    #pragma unroll
    for (int i = 0; i < 8; ++i) {
        long long v = ((const long long*)labels)[i];
        if (v < 0 || v >= VOCAB) is64 = false;
    }
    const int t = blockIdx.x;
    const int lab = is64 ? (int)((const long long*)labels)[t]
                         : ((const int*)labels)[t];
    const float4* hp = (const float4*)(h + (long)t * DIM);
    const float4* wp = (const float4*)(W + (long)lab * DIM);
    float s = 0.f;
    #pragma unroll
    for (int j = 0; j < 2; ++j) {
        const float4 a = hp[threadIdx.x + j * 256];
        const float4 b = wp[threadIdx.x + j * 256];
        s += a.x * b.x + a.y * b.y + a.z * b.z + a.w * b.w;
    }
    #pragma unroll
    for (int msk = 1; msk < 64; msk <<= 1) s += __shfl_xor(s, msk, 64);
    __shared__ float ps[4];
    if ((threadIdx.x & 63) == 0) ps[threadIdx.x >> 6] = s;
    __syncthreads();
    if (threadIdx.x == 0) lab_logit[t] = ps[0] + ps[1] + ps[2] + ps[3];
}

// ---------------------------------------------------- per-token LSE merge ---
__global__ __launch_bounds__(256) void finalize_nll(
    const float* __restrict__ part_m, const float* __restrict__ part_s,
    const float* __restrict__ lab_logit, const float* __restrict__ wts,
    float* __restrict__ wnll)
{
    const int t    = blockIdx.x * 4 + (threadIdx.x >> 6);  // one wave / token
    const int lane = threadIdx.x & 63;
    float m = -3.4e38f, s = 0.f;
    #pragma unroll
    for (int j = 0; j < 4; ++j) {
        const int c = j * 64 + lane;
        const float pm = part_m[(long)t * NCH + c];
        const float ps = part_s[(long)t * NCH + c];
        const float M = fmaxf(m, pm);
        s = s * __expf(m - M) + ps * __expf(pm - M);
        m = M;
    }
    #pragma unroll
    for (int msk = 1; msk < 64; msk <<= 1) {
        const float om = __shfl_xor(m, msk, 64);
        const float os = __shfl_xor(s, msk, 64);
        const float M = fmaxf(m, om);
        s = s * __expf(m - M) + os * __expf(om - M);
        m = M;
    }
    if (lane == 0) {
        const float lse = m + logf(s);
        wnll[t] = wts[t] * (lse - lab_logit[t]);
    }
}

// -------------------------------------------------- deterministic reduce ----
__global__ __launch_bounds__(1024) void final_reduce(
    const float* __restrict__ wnll, const float* __restrict__ wts,
    float* __restrict__ out)
{
    float a = 0.f, b = 0.f;
    #pragma unroll
    for (int j = 0; j < 4; ++j) {
        const int i = threadIdx.x + j * 1024;
        a += wnll[i];
        b += wts[i];
    }
    #pragma unroll
    for (int msk = 1; msk < 64; msk <<= 1) {
        a += __shfl_xor(a, msk, 64);
        b += __shfl_xor(b, msk, 64);
    }
    __shared__ float pa[16], pb[16];
    if ((threadIdx.x & 63) == 0) {
        pa[threadIdx.x >> 6] = a;
        pb[threadIdx.x >> 6] = b;
    }
    __syncthreads();
    if (threadIdx.x == 0) {
        float A = 0.f, B = 0.f;
        #pragma unroll
        for (int i = 0; i < 16; ++i) { A += pa[i]; B += pb[i]; }
        out[0] = A / B;
    }
}

// ----------------------------------------------------------------- launch ---
extern "C" void kernel_launch(void* const* d_in, const int* in_sizes, int n_in,
                              void* d_out, int out_size, void* d_ws, size_t ws_size,
                              hipStream_t stream)
{
    const float* h      = (const float*)d_in[0];
    const void*  labels = d_in[1];
    const float* wts    = (const float*)d_in[2];
    const float* W      = (const float*)d_in[3];
    float* out = (float*)d_out;

    char* ws = (char*)d_ws;
    unsigned char*  h8        = (unsigned char*)(ws);                  //  8 MB
    float*          part_m    = (float*)(ws + (16u << 20));            //  4 MB
    float*          part_s    = (float*)(ws + (24u << 20));            //  4 MB
    float*          lab_logit = (float*)(ws + (32u << 20));            // 16 KB
    float*          wnll      = (float*)(ws + (32u << 20) + 16384);    // 16 KB
    unsigned char*  wseg      = (unsigned char*)(ws + (32u << 20) + 32768);
    const size_t base = (size_t)(32u << 20) + 32768;

    long segmax = 0;
    if (ws_size > base) segmax = (long)((ws_size - base) / (size_t)DIM);
    segmax &= ~255L;
    if (segmax > VOCAB) segmax = VOCAB;
    if (segmax < 256)   segmax = 256;   // require ws_size >= ~33.5 MB

    // 0) h -> fp8 (x16), k-interleaved
    convert_f32_fp8<<<(N_TOK * DIM) / (256 * 8), 256, 0, stream>>>(
        h, h8, (long)N_TOK * DIM, 16.0f);

    // 1) segmented W -> fp8 (x64, k-interleaved) + fused GEMM/LSE partials
    for (long v0 = 0; v0 < VOCAB; v0 += segmax) {
        const long rows = (VOCAB - v0) < segmax ? (VOCAB - v0) : segmax;
        convert_f32_fp8<<<(int)(rows * DIM / (256 * 8)), 256, 0, stream>>>(
            W + v0 * DIM, wseg, rows * (long)DIM, 64.0f);
        const int nwg = (int)(rows / BM) * NTB;
        gemm_lse<<<nwg, 512, 0, stream>>>(h8, wseg, part_m, part_s,
                                          (int)(v0 / BN));
    }

    // 2) exact label logits (fp32)
    label_dot<<<N_TOK, 256, 0, stream>>>(h, W, labels, lab_logit);

    // 3) per-token LSE merge -> w*nll
    finalize_nll<<<N_TOK / 4, 256, 0, stream>>>(part_m, part_s, lab_logit,
                                                wts, wnll);

    // 4) weighted mean
    final_reduce<<<1, 1024, 0, stream>>>(wnll, wts, out);
}

// Round 15
// 765.441 us; speedup vs baseline: 3.8701x; 1.2773x over previous
//
#include <hip/hip_runtime.h>

// ---------------------------------------------------------------------------
// FusedSparseLMHead: weighted-mean CE over h @ W^T without materializing logits.
//   h: [4096, 2048] f32, W: [65536, 2048] f32, labels: [4096] int, w: [4096] f32
// Round 15: int8 GEMM via mfma_i32_16x16x64_i8 (2x K per instruction vs fp8;
//   i32x4 operands = exactly one ds_read_b128, zero repacking; i32 accum is
//   EXACT). Quantization: h_q = rne(h*16) clamp +-127 (step 1/16), W_q =
//   rne(W*1024) (step ~0.001 -- more precise than fp8 on 0.02-scale W);
//   epilogue logits = (float)acc / 16384 (exact pow2). Label logit fp32 exact.
//   Plain contiguous k layout (NO interleave: the x64 fragment slice is 16
//   contiguous bytes at (lane>>4)*16). Skeleton = r14 verbatim: 256^2 tile,
//   K-tile 128 B, c^(r&7) both-sides swizzle, 2 phases + 3 barriers/K-tile,
//   A(t+1) staged ph0, B(t+2) staged ph1 after bar2, boundary vmcnt(4)
//   counted (never 0 until last 2 tiles) -- all safety proofs carry.
// ---------------------------------------------------------------------------

typedef __attribute__((ext_vector_type(4)))  float f32x4;
typedef __attribute__((ext_vector_type(8)))  float f32x8;
typedef __attribute__((ext_vector_type(4)))  int   i32x4;

#define N_TOK 4096
#define DIM   2048          // i8 bytes per row
#define VOCAB 65536
#define BM    256
#define BN    256
#define BK    128           // i8 elements per K-tile
#define NT    (DIM / BK)    // 16 K-tiles
#define NCH   (VOCAB / BN)  // 256 vocab chunks
#define NTB   (N_TOK / BM)  // 16 token blocks

__device__ __forceinline__ void gload_lds16(const void* g, void* l) {
    __builtin_amdgcn_global_load_lds(
        (const __attribute__((address_space(1))) void*)g,
        (__attribute__((address_space(3))) void*)l, 16, 0, 0);
}

__device__ __forceinline__ void bar() {
    asm volatile("" ::: "memory");
    __builtin_amdgcn_s_barrier();
    asm volatile("" ::: "memory");
}

// ------------------------------------------------- convert f32 -> int8 -----
__global__ __launch_bounds__(256) void convert_f32_i8(
    const float* __restrict__ src, signed char* __restrict__ dst,
    long n, float scale)
{
    long i = ((long)blockIdx.x * 256 + threadIdx.x) * 8;
    if (i + 8 > n) return;
    f32x8 v = *(const f32x8*)(src + i);
    signed char o[8];
    #pragma unroll
    for (int j = 0; j < 8; ++j) {
        float x = v[j] * scale;
        x = fminf(fmaxf(x, -127.0f), 127.0f);
        o[j] = (signed char)__float2int_rn(x);
    }
    *(uint2*)(dst + i) = *(const uint2*)o;   // plain contiguous, coalesced
}

// ------------------- i8 16x16x64 2-phase/3-barrier 256^2 GEMM+LSE ----------
__global__ __launch_bounds__(512, 2) void gemm_lse(
    const signed char* __restrict__ h8,      // [4096][2048] i8 (x16)
    const signed char* __restrict__ W8,      // [seg_rows][2048] i8 (x1024)
    float* __restrict__ part_m, float* __restrict__ part_s, int chunk0)
{
    __shared__ unsigned char A_lds[2][32768];   // [par][256r x 128B] 64 KB
    __shared__ unsigned char B_lds[2][32768];   // 64 KB

    const int tid  = threadIdx.x;
    const int lane = tid & 63;
    const int w    = tid >> 6;       // wave 0..7
    const int wm   = w >> 2;         // 0..1 : token half (128 rows)
    const int wn   = w & 3;          // 0..3 : vocab quarter (64 cols)

    // bijective XCD-aware remap, token-fastest decode
    const int nwg  = gridDim.x;
    const int orig = blockIdx.x;
    const int q8 = nwg >> 3, r8 = nwg & 7;
    const int xcd = orig & 7;
    const int wg  = (xcd < r8 ? xcd * (q8 + 1) : r8 * (q8 + 1) + (xcd - r8) * q8)
                    + (orig >> 3);
    const int tok_blk = wg & (NTB - 1);
    const int voc_blk = wg >> 4;                 // NTB == 16

    const long arow0 = (long)tok_blk * BM;
    const signed char* Ab = h8 + arow0 * DIM;
    const signed char* Bb = W8 + (long)voc_blk * BN * DIM;

    i32x4 acc[8][4];
    #pragma unroll
    for (int i = 0; i < 8; ++i)
        #pragma unroll
        for (int j = 0; j < 4; ++j)
            acc[i][j] = (i32x4){0, 0, 0, 0};

    // ---- staging (r12-r14 proven): tile = 256r x 8 chunks(16B); 4 sweeps.
    // Sweep j rows [j*64, j*64+64): r = j*64 + (tid>>3), c = tid&7;
    // src chunk c^(r&7) -> LDS[r][c] = G[r][c^(r&7)] (linear dest).
    const long soff = (long)(tid >> 3) * DIM + ((tid & 7) ^ ((tid >> 3) & 7)) * 16;
    const int  sdb  = w * 1024;     // wave-uniform dest base (bytes)

#define SW_A(t, j, PD)                                                        \
    gload_lds16(Ab + (t) * BK + soff + (long)(j) * 64 * DIM,                  \
                (char*)&A_lds[PD][0] + sdb + (j) * 8192);
#define SW_B(t, j, PD)                                                        \
    gload_lds16(Bb + (t) * BK + soff + (long)(j) * 64 * DIM,                  \
                (char*)&B_lds[PD][0] + sdb + (j) * 8192);

    // ---- fragment reads: row = base+lrow; k-group g slice = 16 contiguous
    // bytes at chunk (lane>>4) + 4g, stored at chunk ^ (lane&7). One b128 =
    // one MFMA operand. Same 8-distinct-chunk wave shape as r13/r14.
    const int lrow = lane & 15;
    const int cxe0 = (((lane >> 4) + 0) ^ (lane & 7)) * 16;   // k-group 0
    const int cxe1 = (((lane >> 4) + 4) ^ (lane & 7)) * 16;   // k-group 1

#define LDF2(D, BASE, ROWB)                                                   \
    D[0] = *(const i32x4*)((BASE) + (ROWB) + cxe0);                           \
    D[1] = *(const i32x4*)((BASE) + (ROWB) + cxe1);

    // 32 MFMA per phase: 2 k-groups x 4 m x 4 nf over acc[MB..MB+3].
#define MFMA32(MB, AR)                                                        \
    __builtin_amdgcn_s_setprio(1);                                            \
    _Pragma("unroll")                                                         \
    for (int g = 0; g < 2; ++g)                                               \
        _Pragma("unroll")                                                     \
        for (int m = 0; m < 4; ++m)                                           \
            _Pragma("unroll")                                                 \
            for (int nf = 0; nf < 4; ++nf)                                    \
                acc[(MB) + m][nf] = __builtin_amdgcn_mfma_i32_16x16x64_i8(    \
                    AR[m][g], bR[nf][g], acc[(MB) + m][nf], 0, 0, 0);         \
    __builtin_amdgcn_s_setprio(0);

#define WAITL()                                                               \
    asm volatile("s_waitcnt lgkmcnt(0)" ::: "memory");                        \
    __builtin_amdgcn_sched_barrier(0);

// One K-tile(128): 2 phases, 3 barriers (r14 structure, safety proofs carry).
#define KTILE(P, t)                                                           \
    {                                                                         \
        const char* Ah = (const char*)&A_lds[P][0] + wm * 16384;              \
        const char* Bh = (const char*)&B_lds[P][0] + wn * 8192;               \
        i32x4 bR[4][2], aR[4][2];                                             \
        /* ph0: LDB(8) + LDA mf0-3(8) | stage A(t+1) sweeps 0-3 */            \
        LDF2(bR[0], Bh, 0 * 2048 + lrow * 128)                                \
        LDF2(bR[1], Bh, 1 * 2048 + lrow * 128)                                \
        LDF2(bR[2], Bh, 2 * 2048 + lrow * 128)                                \
        LDF2(bR[3], Bh, 3 * 2048 + lrow * 128)                                \
        LDF2(aR[0], Ah, 0 * 2048 + lrow * 128)                                \
        LDF2(aR[1], Ah, 1 * 2048 + lrow * 128)                                \
        LDF2(aR[2], Ah, 2 * 2048 + lrow * 128)                                \
        LDF2(aR[3], Ah, 3 * 2048 + lrow * 128)                                \
        if ((t) + 1 < NT) {                                                   \
            SW_A((t) + 1, 0, (P) ^ 1) SW_A((t) + 1, 1, (P) ^ 1)               \
            SW_A((t) + 1, 2, (P) ^ 1) SW_A((t) + 1, 3, (P) ^ 1)               \
        }                                                                     \
        bar(); WAITL()                                                        \
        MFMA32(0, aR)                                                         \
        /* ph1: LDA mf4-7(8) | bar2 | stage B(t+2) | lgkm0 | 32 MFMA */       \
        LDF2(aR[0], Ah, 4 * 2048 + lrow * 128)                                \
        LDF2(aR[1], Ah, 5 * 2048 + lrow * 128)                                \
        LDF2(aR[2], Ah, 6 * 2048 + lrow * 128)                                \
        LDF2(aR[3], Ah, 7 * 2048 + lrow * 128)                                \
        bar();                                                                \
        if ((t) + 2 < NT) {                                                   \
            SW_B((t) + 2, 0, P) SW_B((t) + 2, 1, P)                           \
            SW_B((t) + 2, 2, P) SW_B((t) + 2, 3, P)                           \
        }                                                                     \
        WAITL()                                                               \
        MFMA32(4, aR)                                                         \
        if ((t) < NT - 2) { asm volatile("s_waitcnt vmcnt(4)" ::: "memory"); }\
        else              { asm volatile("s_waitcnt vmcnt(0)" ::: "memory"); }\
        bar();                                                                \
    }

    // prologue: A(0)->A[0], B(0)->B[0], B(1)->B[1]; vmcnt(4): A(0),B(0)
    // landed, B(1) floats (drained by boundary(0)'s vmcnt(4) before t=1).
    SW_A(0, 0, 0) SW_A(0, 1, 0) SW_A(0, 2, 0) SW_A(0, 3, 0)
    SW_B(0, 0, 0) SW_B(0, 1, 0) SW_B(0, 2, 0) SW_B(0, 3, 0)
    SW_B(1, 0, 1) SW_B(1, 1, 1) SW_B(1, 2, 1) SW_B(1, 3, 1)
    asm volatile("s_waitcnt vmcnt(4)" ::: "memory");
    bar();

    for (int t = 0; t < NT; t += 2) {
        KTILE(0, t)
        KTILE(1, t + 1)
    }
#undef KTILE
#undef SW_A
#undef SW_B
#undef LDF2
#undef MFMA32
#undef WAITL

    // ---- epilogue: exact dequant (1/16384), per-token (max, sumexp) -------
    // C frag (shape-determined, verified): row = wm*128 + mf*16 +
    // (lane>>4)*4 + r; col = wn*64 + nf*16 + (lane&15).
    const float INV = 1.0f / 16384.0f;
    float* red_m = (float*)&A_lds[0][0];          // 4 KB
    float* red_s = ((float*)&A_lds[0][0]) + 1024; // 4 KB
    #pragma unroll
    for (int mf = 0; mf < 8; ++mf) {
        #pragma unroll
        for (int r = 0; r < 4; ++r) {
            float v0 = (float)acc[mf][0][r] * INV;
            float v1 = (float)acc[mf][1][r] * INV;
            float v2 = (float)acc[mf][2][r] * INV;
            float v3 = (float)acc[mf][3][r] * INV;
            float mx = fmaxf(fmaxf(v0, v1), fmaxf(v2, v3));
            #pragma unroll
            for (int msk = 1; msk < 16; msk <<= 1)
                mx = fmaxf(mx, __shfl_xor(mx, msk, 64));
            float se = __expf(v0 - mx) + __expf(v1 - mx) +
                       __expf(v2 - mx) + __expf(v3 - mx);
            #pragma unroll
            for (int msk = 1; msk < 16; msk <<= 1)
                se += __shfl_xor(se, msk, 64);
            if ((lane & 15) == 0) {
                const int row = wm * 128 + mf * 16 + (lane >> 4) * 4 + r;
                red_m[row * 4 + wn] = mx;
                red_s[row * 4 + wn] = se;
            }
        }
    }
    __syncthreads();
    if (tid < 256) {
        float M = red_m[tid * 4], S = red_s[tid * 4];
        #pragma unroll
        for (int j = 1; j < 4; ++j) {
            const float m2 = red_m[tid * 4 + j], s2 = red_s[tid * 4 + j];
            const float Mn = fmaxf(M, m2);
            S = S * __expf(M - Mn) + s2 * __expf(m2 - Mn);
            M = Mn;
        }
        part_m[(arow0 + tid) * NCH + chunk0 + voc_blk] = M;
        part_s[(arow0 + tid) * NCH + chunk0 + voc_blk] = S;
    }
}

// ------------------------------------------------------- exact label dot ----
__global__ __launch_bounds__(256) void label_dot(
    const float* __restrict__ h, const float* __restrict__ W,
    const void* __restrict__ labels, float* __restrict__ lab_logit)
{
    bool is64 = true;
    #pragma unroll
    for (int i = 0; i < 8; ++i) {
        long long v = ((const long long*)labels)[i];
        if (v < 0 || v >= VOCAB) is64 = false;
    }
    const int t = blockIdx.x;
    const int lab = is64 ? (int)((const long long*)labels)[t]
                         : ((const int*)labels)[t];
    const float4* hp = (const float4*)(h + (long)t * DIM);
    const float4* wp = (const float4*)(W + (long)lab * DIM);
    float s = 0.f;
    #pragma unroll
    for (int j = 0; j < 2; ++j) {
        const float4 a = hp[threadIdx.x + j * 256];
        const float4 b = wp[threadIdx.x + j * 256];
        s += a.x * b.x + a.y * b.y + a.z * b.z + a.w * b.w;
    }
    #pragma unroll
    for (int msk = 1; msk < 64; msk <<= 1) s += __shfl_xor(s, msk, 64);
    __shared__ float ps[4];
    if ((threadIdx.x & 63) == 0) ps[threadIdx.x >> 6] = s;
    __syncthreads();
    if (threadIdx.x == 0) lab_logit[t] = ps[0] + ps[1] + ps[2] + ps[3];
}

// ---------------------------------------------------- per-token LSE merge ---
__global__ __launch_bounds__(256) void finalize_nll(
    const float* __restrict__ part_m, const float* __restrict__ part_s,
    const float* __restrict__ lab_logit, const float* __restrict__ wts,
    float* __restrict__ wnll)
{
    const int t    = blockIdx.x * 4 + (threadIdx.x >> 6);  // one wave / token
    const int lane = threadIdx.x & 63;
    float m = -3.4e38f, s = 0.f;
    #pragma unroll
    for (int j = 0; j < 4; ++j) {
        const int c = j * 64 + lane;
        const float pm = part_m[(long)t * NCH + c];
        const float ps = part_s[(long)t * NCH + c];
        const float M = fmaxf(m, pm);
        s = s * __expf(m - M) + ps * __expf(pm - M);
        m = M;
    }
    #pragma unroll
    for (int msk = 1; msk < 64; msk <<= 1) {
        const float om = __shfl_xor(m, msk, 64);
        const float os = __shfl_xor(s, msk, 64);
        const float M = fmaxf(m, om);
        s = s * __expf(m - M) + os * __expf(om - M);
        m = M;
    }
    if (lane == 0) {
        const float lse = m + logf(s);
        wnll[t] = wts[t] * (lse - lab_logit[t]);
    }
}

// -------------------------------------------------- deterministic reduce ----
__global__ __launch_bounds__(1024) void final_reduce(
    const float* __restrict__ wnll, const float* __restrict__ wts,
    float* __restrict__ out)
{
    float a = 0.f, b = 0.f;
    #pragma unroll
    for (int j = 0; j < 4; ++j) {
        const int i = threadIdx.x + j * 1024;
        a += wnll[i];
        b += wts[i];
    }
    #pragma unroll
    for (int msk = 1; msk < 64; msk <<= 1) {
        a += __shfl_xor(a, msk, 64);
        b += __shfl_xor(b, msk, 64);
    }
    __shared__ float pa[16], pb[16];
    if ((threadIdx.x & 63) == 0) {
        pa[threadIdx.x >> 6] = a;
        pb[threadIdx.x >> 6] = b;
    }
    __syncthreads();
    if (threadIdx.x == 0) {
        float A = 0.f, B = 0.f;
        #pragma unroll
        for (int i = 0; i < 16; ++i) { A += pa[i]; B += pb[i]; }
        out[0] = A / B;
    }
}

// ----------------------------------------------------------------- launch ---
extern "C" void kernel_launch(void* const* d_in, const int* in_sizes, int n_in,
                              void* d_out, int out_size, void* d_ws, size_t ws_size,
                              hipStream_t stream)
{
    const float* h      = (const float*)d_in[0];
    const void*  labels = d_in[1];
    const float* wts    = (const float*)d_in[2];
    const float* W      = (const float*)d_in[3];
    float* out = (float*)d_out;

    char* ws = (char*)d_ws;
    signed char*    h8        = (signed char*)(ws);                    //  8 MB
    float*          part_m    = (float*)(ws + (16u << 20));            //  4 MB
    float*          part_s    = (float*)(ws + (24u << 20));            //  4 MB
    float*          lab_logit = (float*)(ws + (32u << 20));            // 16 KB
    float*          wnll      = (float*)(ws + (32u << 20) + 16384);    // 16 KB
    signed char*    wseg      = (signed char*)(ws + (32u << 20) + 32768);
    const size_t base = (size_t)(32u << 20) + 32768;

    long segmax = 0;
    if (ws_size > base) segmax = (long)((ws_size - base) / (size_t)DIM);
    segmax &= ~255L;
    if (segmax > VOCAB) segmax = VOCAB;
    if (segmax < 256)   segmax = 256;   // require ws_size >= ~33.5 MB

    // 0) h -> i8 (x16)
    convert_f32_i8<<<(N_TOK * DIM) / (256 * 8), 256, 0, stream>>>(
        h, h8, (long)N_TOK * DIM, 16.0f);

    // 1) segmented W -> i8 (x1024) + fused GEMM/LSE partials
    for (long v0 = 0; v0 < VOCAB; v0 += segmax) {
        const long rows = (VOCAB - v0) < segmax ? (VOCAB - v0) : segmax;
        convert_f32_i8<<<(int)(rows * DIM / (256 * 8)), 256, 0, stream>>>(
            W + v0 * DIM, wseg, rows * (long)DIM, 1024.0f);
        const int nwg = (int)(rows / BM) * NTB;
        gemm_lse<<<nwg, 512, 0, stream>>>(h8, wseg, part_m, part_s,
                                          (int)(v0 / BN));
    }

    // 2) exact label logits (fp32)
    label_dot<<<N_TOK, 256, 0, stream>>>(h, W, labels, lab_logit);

    // 3) per-token LSE merge -> w*nll
    finalize_nll<<<N_TOK / 4, 256, 0, stream>>>(part_m, part_s, lab_logit,
                                                wts, wnll);

    // 4) weighted mean
    final_reduce<<<1, 1024, 0, stream>>>(wnll, wts, out);
}